// Round 3
// baseline (815.722 us; speedup 1.0000x reference)
//
#include <hip/hip_runtime.h>

// CRF log-likelihood: B=256, S=2048, L=64, START=62, END=63.
//
// Chunked linear-operator scan on matrix cores:
//   G_c = prod_{s in chunk} diag(l_s)*P  via v_mfma_f32_32x32x16_f16,
//   16 MFMA / step = exact 64x64x64 matmul; combine kernel applies
//   E = G_{NC-1}*...*G_0*e_START in f32 + gold path + LSE.
//
// Round-3: revert the round-2 lag-2 renorm (marginally stable control loop:
// roots e^{+-i pi/3} -> resonant oscillation -> ci blowup -> exp2 inf ->
// inf*0 NaN in MFMA). Back to round-1's PROVEN lag-1 deadbeat law
// (x_{s+1} = g_s - 6), plus a clamp on ci making inf structurally
// impossible. Kept from round 2: CH=128/NC=16 (2x active waves/SIMD),
// shuffled block->(b,c) map, max3-fused fmax tree, s_setprio around MFMA,
// 2-wave combine, 4-way fma chain split, unroll-4 gold gather.
//
// Layout trick (round 1, verified): HW A-slot->k and B-slot->k maps are
// identical, so any self-consistent k-permutation cancels in the contraction.
// k_my(hi,f) = 4*hi + (f&3) + 8*(f>>2) makes acc(C-layout) -> next-B
// conversion entirely in-lane (32 v_cvt_pkrtz, no cross-lane ops).

#define Bsz 256
#define Ssz 2048
#define START_ 62
#define END_ 63
#define PSTRIDE 36   // old fallback kernel

typedef __attribute__((ext_vector_type(2))) _Float16 half2v;
typedef __attribute__((ext_vector_type(8))) _Float16 half8;
typedef __attribute__((ext_vector_type(16))) float f32x16;

__device__ __forceinline__ unsigned pack_pkrtz(float a, float b) {
    auto h = __builtin_amdgcn_cvt_pkrtz(a, b);   // __fp16 ext_vector(2)
    return __builtin_bit_cast(unsigned, h);
}

__device__ __forceinline__ float dot2h(unsigned a, unsigned b, float c) {
#if __has_builtin(__builtin_amdgcn_fdot2)
    return __builtin_amdgcn_fdot2(__builtin_bit_cast(half2v, a),
                                  __builtin_bit_cast(half2v, b), c, false);
#else
    half2v ha = __builtin_bit_cast(half2v, a);
    half2v hb = __builtin_bit_cast(half2v, b);
    c = __builtin_fmaf((float)ha.x, (float)hb.x, c);
    return __builtin_fmaf((float)ha.y, (float)hb.y, c);
#endif
}

__device__ __forceinline__ float wave_sum(float v) {
#pragma unroll
    for (int m = 32; m >= 1; m >>= 1) v += __shfl_xor(v, m, 64);
    return v;
}

// ---------------------------------------------------------------------------
// OLD serial kernel (fallback when workspace is too small).
// ---------------------------------------------------------------------------
#define CRF_STEP(LG)                                                           \
    {                                                                          \
        const float l_ = __builtin_amdgcn_exp2f((LG) * L2E);                   \
        const int nbi_ = __builtin_amdgcn_update_dpp(                          \
            0, __float_as_int(E), 0xB1, 0xf, 0xf, true);                       \
        const unsigned packed_ = pack_pkrtz(E, __int_as_float(nbi_));          \
        float c0 = 0.f, c1 = 0.f, c2 = 0.f, c3 = 0.f;                          \
        float c4 = 0.f, c5 = 0.f, c6 = 0.f, c7 = 0.f;                          \
        _Pragma("unroll")                                                      \
        for (int k8 = 0; k8 < 8; ++k8) {                                       \
            const uint4 q_ = q[k8];                                            \
            const unsigned t0 = (unsigned)__builtin_amdgcn_readlane(           \
                (int)packed_, 8 * k8 + 0);                                     \
            const unsigned t1 = (unsigned)__builtin_amdgcn_readlane(           \
                (int)packed_, 8 * k8 + 2);                                     \
            const unsigned t2 = (unsigned)__builtin_amdgcn_readlane(           \
                (int)packed_, 8 * k8 + 4);                                     \
            const unsigned t3 = (unsigned)__builtin_amdgcn_readlane(           \
                (int)packed_, 8 * k8 + 6);                                     \
            if (k8 & 1) {                                                      \
                c4 = dot2h(t0, q_.x, c4);                                      \
                c5 = dot2h(t1, q_.y, c5);                                      \
                c6 = dot2h(t2, q_.z, c6);                                      \
                c7 = dot2h(t3, q_.w, c7);                                      \
            } else {                                                           \
                c0 = dot2h(t0, q_.x, c0);                                      \
                c1 = dot2h(t1, q_.y, c1);                                      \
                c2 = dot2h(t2, q_.z, c2);                                      \
                c3 = dot2h(t3, q_.w, c3);                                      \
            }                                                                  \
        }                                                                      \
        const float y_ = ((c0 + c1) + (c2 + c3)) + ((c4 + c5) + (c6 + c7));    \
        const float Ey_ = y_ * l_;                                             \
        const int pb_ = __builtin_amdgcn_readlane(__float_as_int(Ey_), 0);     \
        const int ee_ = (pb_ >> 23) & 0xff;                                    \
        const float sc_ = __int_as_float((244 - ee_) << 23);                   \
        E = Ey_ * sc_;                                                         \
        D += ee_ - 117;                                                        \
    }

#define LOAD_QBLOCK()                                                          \
    {                                                                          \
        unsigned off_ = (unsigned)(lane * (PSTRIDE * 4));                      \
        asm volatile("" : "+v"(off_));                                         \
        const uint4* prow_ = (const uint4*)((const char*)Psh + off_);          \
        _Pragma("unroll")                                                      \
        for (int k8 = 0; k8 < 8; ++k8) q[k8] = prow_[k8];                      \
    }

__global__ __launch_bounds__(64)
__attribute__((amdgpu_waves_per_eu(1, 1)))
void crf_kernel(const float* __restrict__ logits,
                const float* __restrict__ transition,
                const int* __restrict__ labels,
                const int* __restrict__ lens,
                float* __restrict__ out)
{
    const int b    = blockIdx.x;
    const int lane = threadIdx.x;
    const float L2E = 1.4426950408889634f;
    const float LN2 = 0.6931471805599453f;

    __shared__ unsigned Psh[64 * PSTRIDE];

    const int len = lens[b];
    const float* lrow = logits + (size_t)b * (Ssz * 64);

#pragma unroll
    for (int k = 0; k < 32; ++k) {
        float p0 = __builtin_amdgcn_exp2f(transition[lane * 64 + 2 * k]     * L2E);
        float p1 = __builtin_amdgcn_exp2f(transition[lane * 64 + 2 * k + 1] * L2E);
        Psh[lane * PSTRIDE + k] = pack_pkrtz(p0, p1);
    }
    asm volatile("s_waitcnt lgkmcnt(0)" ::: "memory");

    float E = (lane == START_) ? 1.0f : 0.0f;
    int   D = 0;

    float lgb[8];
#pragma unroll
    for (int d = 0; d < 8; ++d) {
        int s0 = (d < len) ? d : (len - 1);
        lgb[d] = lrow[s0 * 64 + lane];
    }

    uint4 q[8];
    const int len8 = len & ~7;
    for (int s = 0; s < len8; s += 8) {
        LOAD_QBLOCK();
#pragma unroll
        for (int d = 0; d < 8; ++d) {
            const float lg = lgb[d];
            int pf = s + 8 + d;
            pf = (pf < len) ? pf : (len - 1);
            lgb[d] = lrow[pf * 64 + lane];
            CRF_STEP(lg);
        }
    }
    const int rem = len - len8;
    if (rem) {
        LOAD_QBLOCK();
        for (int d = 0; d < rem; ++d) {
            const float lg = lgb[d];
            CRF_STEP(lg);
        }
    }

    const float Pend = __builtin_amdgcn_exp2f(transition[END_ * 64 + lane] * L2E);
    const float tot  = wave_sum(E * Pend);
    const float norm = LN2 * ((float)D + __builtin_amdgcn_logf(tot));

    const int* lab = labels + (size_t)b * Ssz;
    float g = 0.0f;
    for (int s = lane; s < len; s += 64) {
        const int l1 = lab[s];
        const int l0 = (s == 0) ? START_ : lab[s - 1];
        g += lrow[s * 64 + l1] + transition[l1 * 64 + l0];
    }
    if (lane == 0) g += transition[END_ * 64 + lab[len - 1]];
    const float gold = wave_sum(g);

    if (lane == 0) out[b] = gold - norm;
}

// ---------------------------------------------------------------------------
// Chunked matrix-scan kernels.
// ---------------------------------------------------------------------------

#define MF16(Aop, Bop, Cop) \
    __builtin_amdgcn_mfma_f32_32x32x16_f16((Aop), (Bop), (Cop), 0, 0, 0)

// One step-matmul: acc = (diag(l*2^-ci)*P) * G.  LAG-1 (deadbeat, proven):
// ci applied this step was computed from the previous step's acc max.
// Clamp makes exp2 overflow structurally impossible under any data.
#define STEP_COMPUTE(LGA, LGB)                                                 \
    f32x16 a00, a01, a10, a11;                                                 \
    {                                                                          \
        const float ncf_ = -(float)ci;                                         \
        const float lv0_ = __builtin_amdgcn_exp2f(                             \
            __builtin_fmaf((LGA), L2E, ncf_));                                 \
        const float lv1_ = __builtin_amdgcn_exp2f(                             \
            __builtin_fmaf((LGB), L2E, ncf_));                                 \
        D += ci;                                                               \
        const _Float16 h0_ = (_Float16)lv0_;                                   \
        const _Float16 h1_ = (_Float16)lv1_;                                   \
        const half8 sv0_ = {h0_, h0_, h0_, h0_, h0_, h0_, h0_, h0_};           \
        const half8 sv1_ = {h1_, h1_, h1_, h1_, h1_, h1_, h1_, h1_};           \
        half8 A_;                                                              \
        __builtin_amdgcn_s_setprio(1);                                         \
        A_ = __builtin_bit_cast(half8, PF[0][0]) * sv0_;                       \
        a00 = MF16(A_, __builtin_bit_cast(half8, Bf[0][0]), Z);                \
        a01 = MF16(A_, __builtin_bit_cast(half8, Bf[0][1]), Z);                \
        A_ = __builtin_bit_cast(half8, PF[0][1]) * sv0_;                       \
        a00 = MF16(A_, __builtin_bit_cast(half8, Bf[1][0]), a00);              \
        a01 = MF16(A_, __builtin_bit_cast(half8, Bf[1][1]), a01);              \
        A_ = __builtin_bit_cast(half8, PF[0][2]) * sv0_;                       \
        a00 = MF16(A_, __builtin_bit_cast(half8, Bf[2][0]), a00);              \
        a01 = MF16(A_, __builtin_bit_cast(half8, Bf[2][1]), a01);              \
        A_ = __builtin_bit_cast(half8, PF[0][3]) * sv0_;                       \
        a00 = MF16(A_, __builtin_bit_cast(half8, Bf[3][0]), a00);              \
        a01 = MF16(A_, __builtin_bit_cast(half8, Bf[3][1]), a01);              \
        A_ = __builtin_bit_cast(half8, PF[1][0]) * sv1_;                       \
        a10 = MF16(A_, __builtin_bit_cast(half8, Bf[0][0]), Z);                \
        a11 = MF16(A_, __builtin_bit_cast(half8, Bf[0][1]), Z);                \
        A_ = __builtin_bit_cast(half8, PF[1][1]) * sv1_;                       \
        a10 = MF16(A_, __builtin_bit_cast(half8, Bf[1][0]), a10);              \
        a11 = MF16(A_, __builtin_bit_cast(half8, Bf[1][1]), a11);              \
        A_ = __builtin_bit_cast(half8, PF[1][2]) * sv1_;                       \
        a10 = MF16(A_, __builtin_bit_cast(half8, Bf[2][0]), a10);              \
        a11 = MF16(A_, __builtin_bit_cast(half8, Bf[2][1]), a11);              \
        A_ = __builtin_bit_cast(half8, PF[1][3]) * sv1_;                       \
        a10 = MF16(A_, __builtin_bit_cast(half8, Bf[3][0]), a10);              \
        a11 = MF16(A_, __builtin_bit_cast(half8, Bf[3][1]), a11);              \
        __builtin_amdgcn_s_setprio(0);                                         \
        const float t0_ = fmaxf(fmaxf(a00[0], a00[1]), a00[2]);                \
        const float t1_ = fmaxf(fmaxf(a00[3], a00[4]), a00[5]);                \
        const float t2_ = fmaxf(fmaxf(a00[6], a00[7]), a00[8]);                \
        const float t3_ = fmaxf(fmaxf(a00[9], a00[10]), a00[11]);              \
        const float t4_ = fmaxf(fmaxf(a00[12], a00[13]), a00[14]);             \
        const float ma_ = fmaxf(fmaxf(t0_, t1_), t2_);                         \
        const float mb2_ = fmaxf(fmaxf(t3_, t4_), a00[15]);                    \
        const int mb_ = __builtin_amdgcn_readfirstlane(                        \
            __float_as_int(fmaxf(ma_, mb2_)));                                 \
        int cin_ = ((mb_ >> 23) & 0xff) - 121; /* drive acc toward 2^-6 */     \
        cin_ = (cin_ < -60) ? -60 : cin_;                                      \
        ci = (cin_ > 60) ? 60 : cin_;                                          \
    }

// acc (C layout) -> B fragments, entirely in-lane thanks to k_my choice.
#define TILE_TO_FRAGS(ACC, BD0, BD1)                                           \
    {                                                                          \
        (BD0) = make_uint4(pack_pkrtz(ACC[0], ACC[1]),                         \
                           pack_pkrtz(ACC[2], ACC[3]),                         \
                           pack_pkrtz(ACC[4], ACC[5]),                         \
                           pack_pkrtz(ACC[6], ACC[7]));                        \
        (BD1) = make_uint4(pack_pkrtz(ACC[8], ACC[9]),                         \
                           pack_pkrtz(ACC[10], ACC[11]),                       \
                           pack_pkrtz(ACC[12], ACC[13]),                       \
                           pack_pkrtz(ACC[14], ACC[15]));                      \
    }

#define STEP_FULL(LGA, LGB)                                                    \
    {                                                                          \
        STEP_COMPUTE(LGA, LGB);                                                \
        TILE_TO_FRAGS(a00, Bf[0][0], Bf[1][0]);                                \
        TILE_TO_FRAGS(a01, Bf[0][1], Bf[1][1]);                                \
        TILE_TO_FRAGS(a10, Bf[2][0], Bf[3][0]);                                \
        TILE_TO_FRAGS(a11, Bf[2][1], Bf[3][1]);                                \
    }

// Final step: store raw acc (true G = stored * 2^D) row-major f32 via the
// HW-verified C layout. Coalesced 2x128B per store.
#define STEP_LAST(LGA, LGB)                                                    \
    {                                                                          \
        STEP_COMPUTE(LGA, LGB);                                                \
        float* gout_ = Gws + (size_t)gslot * 4096;                             \
        _Pragma("unroll")                                                      \
        for (int r = 0; r < 16; ++r) {                                         \
            const int row0_ = (r & 3) + 8 * (r >> 2) + 4 * hi;                 \
            gout_[row0_ * 64 + lo5]             = a00[r];                      \
            gout_[row0_ * 64 + 32 + lo5]        = a01[r];                      \
            gout_[(row0_ + 32) * 64 + lo5]      = a10[r];                      \
            gout_[(row0_ + 32) * 64 + 32 + lo5] = a11[r];                      \
        }                                                                      \
        if (lane == 0) Dws[gslot] = D;                                         \
    }

template<int CHT>
__global__ __launch_bounds__(64)
__attribute__((amdgpu_waves_per_eu(4, 4)))
void crf_chunk(const float* __restrict__ logits,
               const float* __restrict__ transition,
               const int* __restrict__ lens,
               float* __restrict__ Gws,
               int* __restrict__ Dws)
{
    const int NCc  = Ssz / CHT;
    const int idx  = blockIdx.x;
    // Shuffled map: decorrelate a CU's resident blocks from a single batch.
    const int c    = idx >> 8;                     // 0..NCc-1
    const int b    = ((idx & 255) + 37 * c) & 255; // bijective per c
    const int lane = threadIdx.x;
    const int lo5  = lane & 31;
    const int hi   = lane >> 5;
    const float L2E = 1.4426950408889634f;

    const int len   = lens[b];
    const int s0    = c * CHT;
    const int gslot = b * NCc + c;
    if (s0 >= len) {                       // identity chunk: combine skips it
        if (lane == 0) Dws[gslot] = 0;
        return;
    }
    const int s1 = (s0 + CHT < len) ? (s0 + CHT) : len;

    // P fragments (A operand), k_my(hi,f) = 4*hi + (f&3) + 8*(f>>2).
    uint4 PF[2][4];
#pragma unroll
    for (int m = 0; m < 2; ++m) {
#pragma unroll
        for (int kb = 0; kb < 4; ++kb) {
            const float* tp = transition + (m * 32 + lo5) * 64 + kb * 16 + 4 * hi;
            const float e0 = __builtin_amdgcn_exp2f(tp[0] * L2E);
            const float e1 = __builtin_amdgcn_exp2f(tp[1] * L2E);
            const float e2 = __builtin_amdgcn_exp2f(tp[2] * L2E);
            const float e3 = __builtin_amdgcn_exp2f(tp[3] * L2E);
            const float e4 = __builtin_amdgcn_exp2f(tp[8] * L2E);
            const float e5 = __builtin_amdgcn_exp2f(tp[9] * L2E);
            const float e6 = __builtin_amdgcn_exp2f(tp[10] * L2E);
            const float e7 = __builtin_amdgcn_exp2f(tp[11] * L2E);
            PF[m][kb] = make_uint4(pack_pkrtz(e0, e1), pack_pkrtz(e2, e3),
                                   pack_pkrtz(e4, e5), pack_pkrtz(e6, e7));
        }
    }

    // B fragments = G, initialized to identity (same k_my convention).
    uint4 Bf[4][2];
#pragma unroll
    for (int kb = 0; kb < 4; ++kb) {
#pragma unroll
        for (int nb = 0; nb < 2; ++nb) {
            const int col = nb * 32 + lo5;
            unsigned dw[4];
#pragma unroll
            for (int j = 0; j < 4; ++j) {
                const int k0 = kb * 16 + 4 * hi + (j >> 1) * 8 + (j & 1) * 2;
                const unsigned lo16 = (k0     == col) ? 0x3C00u : 0u;
                const unsigned hi16 = (k0 + 1 == col) ? 0x3C00u : 0u;
                dw[j] = lo16 | (hi16 << 16);
            }
            Bf[kb][nb] = make_uint4(dw[0], dw[1], dw[2], dw[3]);
        }
    }

    // Opaque zero accumulator seed.
    float z0 = 0.0f;
    asm volatile("" : "+v"(z0));
    f32x16 Z;
#pragma unroll
    for (int i = 0; i < 16; ++i) Z[i] = z0;

    int D  = 0;   // exact log2 of removed scale (wave-uniform)
    int ci = 0;   // scale applied at the current step (lag-1 deadbeat)

    const float* lrow = logits + (size_t)b * (Ssz * 64);
#define CLMP(x) (((x) < s1) ? (x) : (s1 - 1))

    // Rolling 4-deep logit prefetch (2 x 128B coalesced per step).
    float pA0, pA1, pA2, pA3, pB0, pB1, pB2, pB3;
    {
        int sI;
        sI = CLMP(s0 + 0); pA0 = lrow[sI * 64 + lo5]; pB0 = lrow[sI * 64 + 32 + lo5];
        sI = CLMP(s0 + 1); pA1 = lrow[sI * 64 + lo5]; pB1 = lrow[sI * 64 + 32 + lo5];
        sI = CLMP(s0 + 2); pA2 = lrow[sI * 64 + lo5]; pB2 = lrow[sI * 64 + 32 + lo5];
        sI = CLMP(s0 + 3); pA3 = lrow[sI * 64 + lo5]; pB3 = lrow[sI * 64 + 32 + lo5];
    }

    const int nfull = (s1 - s0) - 1;       // steps with B-frag update
    int t = 0;
    for (; t + 4 <= nfull; t += 4) {
        const int sp = s0 + t + 4;
        const int q0i = CLMP(sp), q1i = CLMP(sp + 1), q2i = CLMP(sp + 2), q3i = CLMP(sp + 3);
        const float nA0 = lrow[q0i * 64 + lo5], nB0 = lrow[q0i * 64 + 32 + lo5];
        const float nA1 = lrow[q1i * 64 + lo5], nB1 = lrow[q1i * 64 + 32 + lo5];
        const float nA2 = lrow[q2i * 64 + lo5], nB2 = lrow[q2i * 64 + 32 + lo5];
        const float nA3 = lrow[q3i * 64 + lo5], nB3 = lrow[q3i * 64 + 32 + lo5];
        STEP_FULL(pA0, pB0);
        STEP_FULL(pA1, pB1);
        STEP_FULL(pA2, pB2);
        STEP_FULL(pA3, pB3);
        pA0 = nA0; pB0 = nB0; pA1 = nA1; pB1 = nB1;
        pA2 = nA2; pB2 = nB2; pA3 = nA3; pB3 = nB3;
    }
    const int r_ = nfull - t;              // 0..3 remaining full steps
    if (r_ >= 1) STEP_FULL(pA0, pB0);
    if (r_ >= 2) STEP_FULL(pA1, pB1);
    if (r_ >= 3) STEP_FULL(pA2, pB2);

    float fA = pA0, fB = pB0;
    if (r_ == 1) { fA = pA1; fB = pB1; }
    else if (r_ == 2) { fA = pA2; fB = pB2; }
    else if (r_ == 3) { fA = pA3; fB = pB3; }
    STEP_LAST(fA, fB);
#undef CLMP
}

// Two waves: wave 0 = alpha chain + norm, wave 1 = gold path (independent).
template<int CHT>
__global__ __launch_bounds__(128)
__attribute__((amdgpu_waves_per_eu(1, 2)))
void crf_combine(const float* __restrict__ logits,
                 const float* __restrict__ transition,
                 const int* __restrict__ labels,
                 const int* __restrict__ lens,
                 const float* __restrict__ Gws,
                 const int* __restrict__ Dws,
                 float* __restrict__ out)
{
    const int NCc  = Ssz / CHT;
    const int b    = blockIdx.x;
    const int wid  = threadIdx.x >> 6;
    const int lane = threadIdx.x & 63;
    const float L2E = 1.4426950408889634f;
    const float LN2 = 0.6931471805599453f;
    const int len = lens[b];
    const float* lrow = logits + (size_t)b * (Ssz * 64);

    __shared__ float s_gold;
    float norm = 0.0f;

    if (wid == 1) {
        const int* lab = labels + (size_t)b * Ssz;
        float g = 0.0f;
#pragma unroll 4
        for (int s = lane; s < len; s += 64) {
            const int l1 = lab[s];
            const int l0 = (s == 0) ? START_ : lab[s - 1];
            g += lrow[s * 64 + l1] + transition[l1 * 64 + l0];
        }
        if (lane == 0) g += transition[END_ * 64 + lab[len - 1]];
        const float gold = wave_sum(g);
        if (lane == 0) s_gold = gold;
    } else {
        // E = e_START; apply stored chunk operators left-to-right in f32.
        float E = (lane == START_) ? 1.0f : 0.0f;
        int Dtot = 0;
#pragma unroll 1
        for (int c = 0; c < NCc; ++c) {
            if (c * CHT >= len) break;     // remaining chunks are identity
            const float4* g4 =
                (const float4*)(Gws + (size_t)(b * NCc + c) * 4096 + lane * 64);
            float4 gr[16];
#pragma unroll
            for (int jj = 0; jj < 16; ++jj) gr[jj] = g4[jj];

            const int Ei = __float_as_int(E);
            float Ens[4] = {0.f, 0.f, 0.f, 0.f};   // 4-way chain split
#pragma unroll
            for (int gq = 0; gq < 4; ++gq) {
#pragma unroll
                for (int qq = 0; qq < 4; ++qq) {
                    const int jj = 4 * gq + qq;
                    Ens[gq] = __builtin_fmaf(gr[jj].x,
                        __int_as_float(__builtin_amdgcn_readlane(Ei, 4 * jj + 0)), Ens[gq]);
                    Ens[gq] = __builtin_fmaf(gr[jj].y,
                        __int_as_float(__builtin_amdgcn_readlane(Ei, 4 * jj + 1)), Ens[gq]);
                    Ens[gq] = __builtin_fmaf(gr[jj].z,
                        __int_as_float(__builtin_amdgcn_readlane(Ei, 4 * jj + 2)), Ens[gq]);
                    Ens[gq] = __builtin_fmaf(gr[jj].w,
                        __int_as_float(__builtin_amdgcn_readlane(Ei, 4 * jj + 3)), Ens[gq]);
                }
            }
            const float En = (Ens[0] + Ens[1]) + (Ens[2] + Ens[3]);
            Dtot += Dws[b * NCc + c];

            float mxv = En;                // renorm E to ~2^0 (exact pow2)
#pragma unroll
            for (int m = 32; m >= 1; m >>= 1) mxv = fmaxf(mxv, __shfl_xor(mxv, m, 64));
            const int ee = (__float_as_int(mxv) >> 23) & 0xff;
            const float scn = __int_as_float((254 - ee) << 23);  // 2^(127-ee)
            E = En * scn;
            Dtot += ee - 127;
        }

        const float Pend = __builtin_amdgcn_exp2f(transition[END_ * 64 + lane] * L2E);
        const float tot  = wave_sum(E * Pend);
        norm = LN2 * ((float)Dtot + __builtin_amdgcn_logf(tot));
    }

    __syncthreads();
    if (wid == 0 && lane == 0) out[b] = s_gold - norm;
}

extern "C" void kernel_launch(void* const* d_in, const int* in_sizes, int n_in,
                              void* d_out, int out_size, void* d_ws, size_t ws_size,
                              hipStream_t stream) {
    const float* logits     = (const float*)d_in[0];
    const float* transition = (const float*)d_in[1];
    const int*   labels     = (const int*)d_in[2];
    const int*   lens       = (const int*)d_in[3];
    float*       out        = (float*)d_out;

    const size_t g16  = (size_t)Bsz * 16 * 4096 * sizeof(float);   // 64 MiB
    const size_t n16  = g16 + (size_t)Bsz * 16 * sizeof(int);
    const size_t g8   = (size_t)Bsz * 8 * 4096 * sizeof(float);    // 32 MiB
    const size_t n8   = g8 + (size_t)Bsz * 8 * sizeof(int);

    if (d_ws != nullptr && ws_size >= n16) {
        float* Gws = (float*)d_ws;
        int*   Dws = (int*)((char*)d_ws + g16);
        crf_chunk<128><<<dim3(Bsz * 16), dim3(64), 0, stream>>>(
            logits, transition, lens, Gws, Dws);
        crf_combine<128><<<dim3(Bsz), dim3(128), 0, stream>>>(
            logits, transition, labels, lens, Gws, Dws, out);
    } else if (d_ws != nullptr && ws_size >= n8) {
        float* Gws = (float*)d_ws;
        int*   Dws = (int*)((char*)d_ws + g8);
        crf_chunk<256><<<dim3(Bsz * 8), dim3(64), 0, stream>>>(
            logits, transition, lens, Gws, Dws);
        crf_combine<256><<<dim3(Bsz), dim3(128), 0, stream>>>(
            logits, transition, labels, lens, Gws, Dws, out);
    } else {
        crf_kernel<<<dim3(Bsz), dim3(64), 0, stream>>>(
            logits, transition, labels, lens, out);
    }
}

// Round 5
// 306.537 us; speedup vs baseline: 2.6611x; 2.6611x over previous
//
#include <hip/hip_runtime.h>

// CRF log-likelihood: B=256, S=2048, L=64, START=62, END=63.
//
// Chunked linear-operator scan on matrix cores:
//   G_c = prod_{s in chunk} diag(l_s)*P  via v_mfma_f32_32x32x16_f16,
//   16 MFMA / step = exact 64x64x64 matmul; combine kernel applies
//   E = G_{NC-1}*...*G_0*e_START in f32 + gold path + LSE.
//
// Round-5: IDENTICAL to round-4 (round-4 bench was an infra failure --
// container acquisition -- so the spill-fix hypothesis is still untested).
// Round-4 rationale: round-3's waves_per_eu(4,4) set the unified-file RA
// budget to 128 regs; the kernel's live set is ~156 (PF 32 + Bf 32 +
// acc 64 AGPR + ~28 misc) -> 289 MB/dispatch scratch writes (WRITE_SIZE),
// VGPR 92->64, MfmaUtil 25->8%, 213->663 us. waves_per_eu(3,8): budget
// 170 >= 156 -> no spill, true HW capacity floor(512/156) = 3 waves/SIMD.
// CH=128 (16 blocks/CU launched) keeps a backfill queue per SIMD.
// Numerics unchanged from the round-3 PASS (lag-1 deadbeat renorm +
// ci clamp, absmax 64).
//
// Layout trick (round 1, verified): HW A-slot->k and B-slot->k maps are
// identical, so any self-consistent k-permutation cancels in the contraction.
// k_my(hi,f) = 4*hi + (f&3) + 8*(f>>2) makes acc(C-layout) -> next-B
// conversion entirely in-lane (32 v_cvt_pkrtz, no cross-lane ops).

#define Bsz 256
#define Ssz 2048
#define START_ 62
#define END_ 63
#define PSTRIDE 36   // old fallback kernel

typedef __attribute__((ext_vector_type(2))) _Float16 half2v;
typedef __attribute__((ext_vector_type(8))) _Float16 half8;
typedef __attribute__((ext_vector_type(16))) float f32x16;

__device__ __forceinline__ unsigned pack_pkrtz(float a, float b) {
    auto h = __builtin_amdgcn_cvt_pkrtz(a, b);   // __fp16 ext_vector(2)
    return __builtin_bit_cast(unsigned, h);
}

__device__ __forceinline__ float dot2h(unsigned a, unsigned b, float c) {
#if __has_builtin(__builtin_amdgcn_fdot2)
    return __builtin_amdgcn_fdot2(__builtin_bit_cast(half2v, a),
                                  __builtin_bit_cast(half2v, b), c, false);
#else
    half2v ha = __builtin_bit_cast(half2v, a);
    half2v hb = __builtin_bit_cast(half2v, b);
    c = __builtin_fmaf((float)ha.x, (float)hb.x, c);
    return __builtin_fmaf((float)ha.y, (float)hb.y, c);
#endif
}

__device__ __forceinline__ float wave_sum(float v) {
#pragma unroll
    for (int m = 32; m >= 1; m >>= 1) v += __shfl_xor(v, m, 64);
    return v;
}

// ---------------------------------------------------------------------------
// OLD serial kernel (fallback when workspace is too small).
// ---------------------------------------------------------------------------
#define CRF_STEP(LG)                                                           \
    {                                                                          \
        const float l_ = __builtin_amdgcn_exp2f((LG) * L2E);                   \
        const int nbi_ = __builtin_amdgcn_update_dpp(                          \
            0, __float_as_int(E), 0xB1, 0xf, 0xf, true);                       \
        const unsigned packed_ = pack_pkrtz(E, __int_as_float(nbi_));          \
        float c0 = 0.f, c1 = 0.f, c2 = 0.f, c3 = 0.f;                          \
        float c4 = 0.f, c5 = 0.f, c6 = 0.f, c7 = 0.f;                          \
        _Pragma("unroll")                                                      \
        for (int k8 = 0; k8 < 8; ++k8) {                                       \
            const uint4 q_ = q[k8];                                            \
            const unsigned t0 = (unsigned)__builtin_amdgcn_readlane(           \
                (int)packed_, 8 * k8 + 0);                                     \
            const unsigned t1 = (unsigned)__builtin_amdgcn_readlane(           \
                (int)packed_, 8 * k8 + 2);                                     \
            const unsigned t2 = (unsigned)__builtin_amdgcn_readlane(           \
                (int)packed_, 8 * k8 + 4);                                     \
            const unsigned t3 = (unsigned)__builtin_amdgcn_readlane(           \
                (int)packed_, 8 * k8 + 6);                                     \
            if (k8 & 1) {                                                      \
                c4 = dot2h(t0, q_.x, c4);                                      \
                c5 = dot2h(t1, q_.y, c5);                                      \
                c6 = dot2h(t2, q_.z, c6);                                      \
                c7 = dot2h(t3, q_.w, c7);                                      \
            } else {                                                           \
                c0 = dot2h(t0, q_.x, c0);                                      \
                c1 = dot2h(t1, q_.y, c1);                                      \
                c2 = dot2h(t2, q_.z, c2);                                      \
                c3 = dot2h(t3, q_.w, c3);                                      \
            }                                                                  \
        }                                                                      \
        const float y_ = ((c0 + c1) + (c2 + c3)) + ((c4 + c5) + (c6 + c7));    \
        const float Ey_ = y_ * l_;                                             \
        const int pb_ = __builtin_amdgcn_readlane(__float_as_int(Ey_), 0);     \
        const int ee_ = (pb_ >> 23) & 0xff;                                    \
        const float sc_ = __int_as_float((244 - ee_) << 23);                   \
        E = Ey_ * sc_;                                                         \
        D += ee_ - 117;                                                        \
    }

#define LOAD_QBLOCK()                                                          \
    {                                                                          \
        unsigned off_ = (unsigned)(lane * (PSTRIDE * 4));                      \
        asm volatile("" : "+v"(off_));                                         \
        const uint4* prow_ = (const uint4*)((const char*)Psh + off_);          \
        _Pragma("unroll")                                                      \
        for (int k8 = 0; k8 < 8; ++k8) q[k8] = prow_[k8];                      \
    }

__global__ __launch_bounds__(64)
__attribute__((amdgpu_waves_per_eu(1, 1)))
void crf_kernel(const float* __restrict__ logits,
                const float* __restrict__ transition,
                const int* __restrict__ labels,
                const int* __restrict__ lens,
                float* __restrict__ out)
{
    const int b    = blockIdx.x;
    const int lane = threadIdx.x;
    const float L2E = 1.4426950408889634f;
    const float LN2 = 0.6931471805599453f;

    __shared__ unsigned Psh[64 * PSTRIDE];

    const int len = lens[b];
    const float* lrow = logits + (size_t)b * (Ssz * 64);

#pragma unroll
    for (int k = 0; k < 32; ++k) {
        float p0 = __builtin_amdgcn_exp2f(transition[lane * 64 + 2 * k]     * L2E);
        float p1 = __builtin_amdgcn_exp2f(transition[lane * 64 + 2 * k + 1] * L2E);
        Psh[lane * PSTRIDE + k] = pack_pkrtz(p0, p1);
    }
    asm volatile("s_waitcnt lgkmcnt(0)" ::: "memory");

    float E = (lane == START_) ? 1.0f : 0.0f;
    int   D = 0;

    float lgb[8];
#pragma unroll
    for (int d = 0; d < 8; ++d) {
        int s0 = (d < len) ? d : (len - 1);
        lgb[d] = lrow[s0 * 64 + lane];
    }

    uint4 q[8];
    const int len8 = len & ~7;
    for (int s = 0; s < len8; s += 8) {
        LOAD_QBLOCK();
#pragma unroll
        for (int d = 0; d < 8; ++d) {
            const float lg = lgb[d];
            int pf = s + 8 + d;
            pf = (pf < len) ? pf : (len - 1);
            lgb[d] = lrow[pf * 64 + lane];
            CRF_STEP(lg);
        }
    }
    const int rem = len - len8;
    if (rem) {
        LOAD_QBLOCK();
        for (int d = 0; d < rem; ++d) {
            const float lg = lgb[d];
            CRF_STEP(lg);
        }
    }

    const float Pend = __builtin_amdgcn_exp2f(transition[END_ * 64 + lane] * L2E);
    const float tot  = wave_sum(E * Pend);
    const float norm = LN2 * ((float)D + __builtin_amdgcn_logf(tot));

    const int* lab = labels + (size_t)b * Ssz;
    float g = 0.0f;
    for (int s = lane; s < len; s += 64) {
        const int l1 = lab[s];
        const int l0 = (s == 0) ? START_ : lab[s - 1];
        g += lrow[s * 64 + l1] + transition[l1 * 64 + l0];
    }
    if (lane == 0) g += transition[END_ * 64 + lab[len - 1]];
    const float gold = wave_sum(g);

    if (lane == 0) out[b] = gold - norm;
}

// ---------------------------------------------------------------------------
// Chunked matrix-scan kernels.
// ---------------------------------------------------------------------------

#define MF16(Aop, Bop, Cop) \
    __builtin_amdgcn_mfma_f32_32x32x16_f16((Aop), (Bop), (Cop), 0, 0, 0)

// One step-matmul: acc = (diag(l*2^-ci)*P) * G.  LAG-1 (deadbeat, proven):
// ci applied this step was computed from the previous step's acc max.
// Clamp makes exp2 overflow structurally impossible under any data.
#define STEP_COMPUTE(LGA, LGB)                                                 \
    f32x16 a00, a01, a10, a11;                                                 \
    {                                                                          \
        const float ncf_ = -(float)ci;                                         \
        const float lv0_ = __builtin_amdgcn_exp2f(                             \
            __builtin_fmaf((LGA), L2E, ncf_));                                 \
        const float lv1_ = __builtin_amdgcn_exp2f(                             \
            __builtin_fmaf((LGB), L2E, ncf_));                                 \
        D += ci;                                                               \
        const _Float16 h0_ = (_Float16)lv0_;                                   \
        const _Float16 h1_ = (_Float16)lv1_;                                   \
        const half8 sv0_ = {h0_, h0_, h0_, h0_, h0_, h0_, h0_, h0_};           \
        const half8 sv1_ = {h1_, h1_, h1_, h1_, h1_, h1_, h1_, h1_};           \
        half8 A_;                                                              \
        __builtin_amdgcn_s_setprio(1);                                         \
        A_ = __builtin_bit_cast(half8, PF[0][0]) * sv0_;                       \
        a00 = MF16(A_, __builtin_bit_cast(half8, Bf[0][0]), Z);                \
        a01 = MF16(A_, __builtin_bit_cast(half8, Bf[0][1]), Z);                \
        A_ = __builtin_bit_cast(half8, PF[0][1]) * sv0_;                       \
        a00 = MF16(A_, __builtin_bit_cast(half8, Bf[1][0]), a00);              \
        a01 = MF16(A_, __builtin_bit_cast(half8, Bf[1][1]), a01);              \
        A_ = __builtin_bit_cast(half8, PF[0][2]) * sv0_;                       \
        a00 = MF16(A_, __builtin_bit_cast(half8, Bf[2][0]), a00);              \
        a01 = MF16(A_, __builtin_bit_cast(half8, Bf[2][1]), a01);              \
        A_ = __builtin_bit_cast(half8, PF[0][3]) * sv0_;                       \
        a00 = MF16(A_, __builtin_bit_cast(half8, Bf[3][0]), a00);              \
        a01 = MF16(A_, __builtin_bit_cast(half8, Bf[3][1]), a01);              \
        A_ = __builtin_bit_cast(half8, PF[1][0]) * sv1_;                       \
        a10 = MF16(A_, __builtin_bit_cast(half8, Bf[0][0]), Z);                \
        a11 = MF16(A_, __builtin_bit_cast(half8, Bf[0][1]), Z);                \
        A_ = __builtin_bit_cast(half8, PF[1][1]) * sv1_;                       \
        a10 = MF16(A_, __builtin_bit_cast(half8, Bf[1][0]), a10);              \
        a11 = MF16(A_, __builtin_bit_cast(half8, Bf[1][1]), a11);              \
        A_ = __builtin_bit_cast(half8, PF[1][2]) * sv1_;                       \
        a10 = MF16(A_, __builtin_bit_cast(half8, Bf[2][0]), a10);              \
        a11 = MF16(A_, __builtin_bit_cast(half8, Bf[2][1]), a11);              \
        A_ = __builtin_bit_cast(half8, PF[1][3]) * sv1_;                       \
        a10 = MF16(A_, __builtin_bit_cast(half8, Bf[3][0]), a10);              \
        a11 = MF16(A_, __builtin_bit_cast(half8, Bf[3][1]), a11);              \
        __builtin_amdgcn_s_setprio(0);                                         \
        const float t0_ = fmaxf(fmaxf(a00[0], a00[1]), a00[2]);                \
        const float t1_ = fmaxf(fmaxf(a00[3], a00[4]), a00[5]);                \
        const float t2_ = fmaxf(fmaxf(a00[6], a00[7]), a00[8]);                \
        const float t3_ = fmaxf(fmaxf(a00[9], a00[10]), a00[11]);              \
        const float t4_ = fmaxf(fmaxf(a00[12], a00[13]), a00[14]);             \
        const float ma_ = fmaxf(fmaxf(t0_, t1_), t2_);                         \
        const float mb2_ = fmaxf(fmaxf(t3_, t4_), a00[15]);                    \
        const int mb_ = __builtin_amdgcn_readfirstlane(                        \
            __float_as_int(fmaxf(ma_, mb2_)));                                 \
        int cin_ = ((mb_ >> 23) & 0xff) - 121; /* drive acc toward 2^-6 */     \
        cin_ = (cin_ < -60) ? -60 : cin_;                                      \
        ci = (cin_ > 60) ? 60 : cin_;                                          \
    }

// acc (C layout) -> B fragments, entirely in-lane thanks to k_my choice.
#define TILE_TO_FRAGS(ACC, BD0, BD1)                                           \
    {                                                                          \
        (BD0) = make_uint4(pack_pkrtz(ACC[0], ACC[1]),                         \
                           pack_pkrtz(ACC[2], ACC[3]),                         \
                           pack_pkrtz(ACC[4], ACC[5]),                         \
                           pack_pkrtz(ACC[6], ACC[7]));                        \
        (BD1) = make_uint4(pack_pkrtz(ACC[8], ACC[9]),                         \
                           pack_pkrtz(ACC[10], ACC[11]),                       \
                           pack_pkrtz(ACC[12], ACC[13]),                       \
                           pack_pkrtz(ACC[14], ACC[15]));                      \
    }

#define STEP_FULL(LGA, LGB)                                                    \
    {                                                                          \
        STEP_COMPUTE(LGA, LGB);                                                \
        TILE_TO_FRAGS(a00, Bf[0][0], Bf[1][0]);                                \
        TILE_TO_FRAGS(a01, Bf[0][1], Bf[1][1]);                                \
        TILE_TO_FRAGS(a10, Bf[2][0], Bf[3][0]);                                \
        TILE_TO_FRAGS(a11, Bf[2][1], Bf[3][1]);                                \
    }

// Final step: store raw acc (true G = stored * 2^D) row-major f32 via the
// HW-verified C layout. Coalesced 2x128B per store.
#define STEP_LAST(LGA, LGB)                                                    \
    {                                                                          \
        STEP_COMPUTE(LGA, LGB);                                                \
        float* gout_ = Gws + (size_t)gslot * 4096;                             \
        _Pragma("unroll")                                                      \
        for (int r = 0; r < 16; ++r) {                                         \
            const int row0_ = (r & 3) + 8 * (r >> 2) + 4 * hi;                 \
            gout_[row0_ * 64 + lo5]             = a00[r];                      \
            gout_[row0_ * 64 + 32 + lo5]        = a01[r];                      \
            gout_[(row0_ + 32) * 64 + lo5]      = a10[r];                      \
            gout_[(row0_ + 32) * 64 + 32 + lo5] = a11[r];                      \
        }                                                                      \
        if (lane == 0) Dws[gslot] = D;                                         \
    }

template<int CHT>
__global__ __launch_bounds__(64)
__attribute__((amdgpu_waves_per_eu(3, 8)))
void crf_chunk(const float* __restrict__ logits,
               const float* __restrict__ transition,
               const int* __restrict__ lens,
               float* __restrict__ Gws,
               int* __restrict__ Dws)
{
    const int NCc  = Ssz / CHT;
    const int idx  = blockIdx.x;
    // Shuffled map: decorrelate a CU's resident blocks from a single batch.
    const int c    = idx >> 8;                     // 0..NCc-1
    const int b    = ((idx & 255) + 37 * c) & 255; // bijective per c
    const int lane = threadIdx.x;
    const int lo5  = lane & 31;
    const int hi   = lane >> 5;
    const float L2E = 1.4426950408889634f;

    const int len   = lens[b];
    const int s0    = c * CHT;
    const int gslot = b * NCc + c;
    if (s0 >= len) {                       // identity chunk: combine skips it
        if (lane == 0) Dws[gslot] = 0;
        return;
    }
    const int s1 = (s0 + CHT < len) ? (s0 + CHT) : len;

    // P fragments (A operand), k_my(hi,f) = 4*hi + (f&3) + 8*(f>>2).
    uint4 PF[2][4];
#pragma unroll
    for (int m = 0; m < 2; ++m) {
#pragma unroll
        for (int kb = 0; kb < 4; ++kb) {
            const float* tp = transition + (m * 32 + lo5) * 64 + kb * 16 + 4 * hi;
            const float e0 = __builtin_amdgcn_exp2f(tp[0] * L2E);
            const float e1 = __builtin_amdgcn_exp2f(tp[1] * L2E);
            const float e2 = __builtin_amdgcn_exp2f(tp[2] * L2E);
            const float e3 = __builtin_amdgcn_exp2f(tp[3] * L2E);
            const float e4 = __builtin_amdgcn_exp2f(tp[8] * L2E);
            const float e5 = __builtin_amdgcn_exp2f(tp[9] * L2E);
            const float e6 = __builtin_amdgcn_exp2f(tp[10] * L2E);
            const float e7 = __builtin_amdgcn_exp2f(tp[11] * L2E);
            PF[m][kb] = make_uint4(pack_pkrtz(e0, e1), pack_pkrtz(e2, e3),
                                   pack_pkrtz(e4, e5), pack_pkrtz(e6, e7));
        }
    }

    // B fragments = G, initialized to identity (same k_my convention).
    uint4 Bf[4][2];
#pragma unroll
    for (int kb = 0; kb < 4; ++kb) {
#pragma unroll
        for (int nb = 0; nb < 2; ++nb) {
            const int col = nb * 32 + lo5;
            unsigned dw[4];
#pragma unroll
            for (int j = 0; j < 4; ++j) {
                const int k0 = kb * 16 + 4 * hi + (j >> 1) * 8 + (j & 1) * 2;
                const unsigned lo16 = (k0     == col) ? 0x3C00u : 0u;
                const unsigned hi16 = (k0 + 1 == col) ? 0x3C00u : 0u;
                dw[j] = lo16 | (hi16 << 16);
            }
            Bf[kb][nb] = make_uint4(dw[0], dw[1], dw[2], dw[3]);
        }
    }

    // Opaque zero accumulator seed.
    float z0 = 0.0f;
    asm volatile("" : "+v"(z0));
    f32x16 Z;
#pragma unroll
    for (int i = 0; i < 16; ++i) Z[i] = z0;

    int D  = 0;   // exact log2 of removed scale (wave-uniform)
    int ci = 0;   // scale applied at the current step (lag-1 deadbeat)

    const float* lrow = logits + (size_t)b * (Ssz * 64);
#define CLMP(x) (((x) < s1) ? (x) : (s1 - 1))

    // Rolling 4-deep logit prefetch (2 x 128B coalesced per step).
    float pA0, pA1, pA2, pA3, pB0, pB1, pB2, pB3;
    {
        int sI;
        sI = CLMP(s0 + 0); pA0 = lrow[sI * 64 + lo5]; pB0 = lrow[sI * 64 + 32 + lo5];
        sI = CLMP(s0 + 1); pA1 = lrow[sI * 64 + lo5]; pB1 = lrow[sI * 64 + 32 + lo5];
        sI = CLMP(s0 + 2); pA2 = lrow[sI * 64 + lo5]; pB2 = lrow[sI * 64 + 32 + lo5];
        sI = CLMP(s0 + 3); pA3 = lrow[sI * 64 + lo5]; pB3 = lrow[sI * 64 + 32 + lo5];
    }

    const int nfull = (s1 - s0) - 1;       // steps with B-frag update
    int t = 0;
    for (; t + 4 <= nfull; t += 4) {
        const int sp = s0 + t + 4;
        const int q0i = CLMP(sp), q1i = CLMP(sp + 1), q2i = CLMP(sp + 2), q3i = CLMP(sp + 3);
        const float nA0 = lrow[q0i * 64 + lo5], nB0 = lrow[q0i * 64 + 32 + lo5];
        const float nA1 = lrow[q1i * 64 + lo5], nB1 = lrow[q1i * 64 + 32 + lo5];
        const float nA2 = lrow[q2i * 64 + lo5], nB2 = lrow[q2i * 64 + 32 + lo5];
        const float nA3 = lrow[q3i * 64 + lo5], nB3 = lrow[q3i * 64 + 32 + lo5];
        STEP_FULL(pA0, pB0);
        STEP_FULL(pA1, pB1);
        STEP_FULL(pA2, pB2);
        STEP_FULL(pA3, pB3);
        pA0 = nA0; pB0 = nB0; pA1 = nA1; pB1 = nB1;
        pA2 = nA2; pB2 = nB2; pA3 = nA3; pB3 = nB3;
    }
    const int r_ = nfull - t;              // 0..3 remaining full steps
    if (r_ >= 1) STEP_FULL(pA0, pB0);
    if (r_ >= 2) STEP_FULL(pA1, pB1);
    if (r_ >= 3) STEP_FULL(pA2, pB2);

    float fA = pA0, fB = pB0;
    if (r_ == 1) { fA = pA1; fB = pB1; }
    else if (r_ == 2) { fA = pA2; fB = pB2; }
    else if (r_ == 3) { fA = pA3; fB = pB3; }
    STEP_LAST(fA, fB);
#undef CLMP
}

// Two waves: wave 0 = alpha chain + norm, wave 1 = gold path (independent).
template<int CHT>
__global__ __launch_bounds__(128)
__attribute__((amdgpu_waves_per_eu(1, 2)))
void crf_combine(const float* __restrict__ logits,
                 const float* __restrict__ transition,
                 const int* __restrict__ labels,
                 const int* __restrict__ lens,
                 const float* __restrict__ Gws,
                 const int* __restrict__ Dws,
                 float* __restrict__ out)
{
    const int NCc  = Ssz / CHT;
    const int b    = blockIdx.x;
    const int wid  = threadIdx.x >> 6;
    const int lane = threadIdx.x & 63;
    const float L2E = 1.4426950408889634f;
    const float LN2 = 0.6931471805599453f;
    const int len = lens[b];
    const float* lrow = logits + (size_t)b * (Ssz * 64);

    __shared__ float s_gold;
    float norm = 0.0f;

    if (wid == 1) {
        const int* lab = labels + (size_t)b * Ssz;
        float g = 0.0f;
#pragma unroll 4
        for (int s = lane; s < len; s += 64) {
            const int l1 = lab[s];
            const int l0 = (s == 0) ? START_ : lab[s - 1];
            g += lrow[s * 64 + l1] + transition[l1 * 64 + l0];
        }
        if (lane == 0) g += transition[END_ * 64 + lab[len - 1]];
        const float gold = wave_sum(g);
        if (lane == 0) s_gold = gold;
    } else {
        // E = e_START; apply stored chunk operators left-to-right in f32.
        float E = (lane == START_) ? 1.0f : 0.0f;
        int Dtot = 0;
#pragma unroll 1
        for (int c = 0; c < NCc; ++c) {
            if (c * CHT >= len) break;     // remaining chunks are identity
            const float4* g4 =
                (const float4*)(Gws + (size_t)(b * NCc + c) * 4096 + lane * 64);
            float4 gr[16];
#pragma unroll
            for (int jj = 0; jj < 16; ++jj) gr[jj] = g4[jj];

            const int Ei = __float_as_int(E);
            float Ens[4] = {0.f, 0.f, 0.f, 0.f};   // 4-way chain split
#pragma unroll
            for (int gq = 0; gq < 4; ++gq) {
#pragma unroll
                for (int qq = 0; qq < 4; ++qq) {
                    const int jj = 4 * gq + qq;
                    Ens[gq] = __builtin_fmaf(gr[jj].x,
                        __int_as_float(__builtin_amdgcn_readlane(Ei, 4 * jj + 0)), Ens[gq]);
                    Ens[gq] = __builtin_fmaf(gr[jj].y,
                        __int_as_float(__builtin_amdgcn_readlane(Ei, 4 * jj + 1)), Ens[gq]);
                    Ens[gq] = __builtin_fmaf(gr[jj].z,
                        __int_as_float(__builtin_amdgcn_readlane(Ei, 4 * jj + 2)), Ens[gq]);
                    Ens[gq] = __builtin_fmaf(gr[jj].w,
                        __int_as_float(__builtin_amdgcn_readlane(Ei, 4 * jj + 3)), Ens[gq]);
                }
            }
            const float En = (Ens[0] + Ens[1]) + (Ens[2] + Ens[3]);
            Dtot += Dws[b * NCc + c];

            float mxv = En;                // renorm E to ~2^0 (exact pow2)
#pragma unroll
            for (int m = 32; m >= 1; m >>= 1) mxv = fmaxf(mxv, __shfl_xor(mxv, m, 64));
            const int ee = (__float_as_int(mxv) >> 23) & 0xff;
            const float scn = __int_as_float((254 - ee) << 23);  // 2^(127-ee)
            E = En * scn;
            Dtot += ee - 127;
        }

        const float Pend = __builtin_amdgcn_exp2f(transition[END_ * 64 + lane] * L2E);
        const float tot  = wave_sum(E * Pend);
        norm = LN2 * ((float)Dtot + __builtin_amdgcn_logf(tot));
    }

    __syncthreads();
    if (wid == 0 && lane == 0) out[b] = s_gold - norm;
}

extern "C" void kernel_launch(void* const* d_in, const int* in_sizes, int n_in,
                              void* d_out, int out_size, void* d_ws, size_t ws_size,
                              hipStream_t stream) {
    const float* logits     = (const float*)d_in[0];
    const float* transition = (const float*)d_in[1];
    const int*   labels     = (const int*)d_in[2];
    const int*   lens       = (const int*)d_in[3];
    float*       out        = (float*)d_out;

    const size_t g16  = (size_t)Bsz * 16 * 4096 * sizeof(float);   // 64 MiB
    const size_t n16  = g16 + (size_t)Bsz * 16 * sizeof(int);
    const size_t g8   = (size_t)Bsz * 8 * 4096 * sizeof(float);    // 32 MiB
    const size_t n8   = g8 + (size_t)Bsz * 8 * sizeof(int);

    if (d_ws != nullptr && ws_size >= n16) {
        float* Gws = (float*)d_ws;
        int*   Dws = (int*)((char*)d_ws + g16);
        crf_chunk<128><<<dim3(Bsz * 16), dim3(64), 0, stream>>>(
            logits, transition, lens, Gws, Dws);
        crf_combine<128><<<dim3(Bsz), dim3(128), 0, stream>>>(
            logits, transition, labels, lens, Gws, Dws, out);
    } else if (d_ws != nullptr && ws_size >= n8) {
        float* Gws = (float*)d_ws;
        int*   Dws = (int*)((char*)d_ws + g8);
        crf_chunk<256><<<dim3(Bsz * 8), dim3(64), 0, stream>>>(
            logits, transition, lens, Gws, Dws);
        crf_combine<256><<<dim3(Bsz), dim3(128), 0, stream>>>(
            logits, transition, labels, lens, Gws, Dws, out);
    } else {
        crf_kernel<<<dim3(Bsz), dim3(64), 0, stream>>>(
            logits, transition, labels, lens, out);
    }
}